// Round 7
// baseline (832.990 us; speedup 1.0000x reference)
//
#include <hip/hip_runtime.h>
#include <math.h>

#define B_     32
#define S_     1024
#define H2_    1024
#define TOPIC_ 256

__device__ __forceinline__ float fast_tanh(float x) {
    // tanh(x) = 1 - 2/(exp(2x)+1); saturates to +-1 at extremes.
    float e = __expf(2.0f * x);
    return 1.0f - 2.0f / (e + 1.0f);
}

// Kernel 1: combined[b][h] = sum_k s[b][k]*W_s[k][h] + sum_j hz[b][j]*W_z[j][h] + b_c[h]
// grid = (H2/32, B) = (32, 32), block = 256 (8 k-chunks x 32 h)
// Also zeroes the per-batch completion counters used by kernel 2's fused
// softmax (runs before it in the same stream -> visibility guaranteed).
__global__ __launch_bounds__(256) void combined_kernel(
    const float* __restrict__ s,    // [B, H2]
    const float* __restrict__ hz,   // [B, TOPIC]
    const float* __restrict__ W_s,  // [H2, H2]  (in, out)
    const float* __restrict__ W_z,  // [TOPIC, H2]
    const float* __restrict__ b_c,  // [H2]
    float* __restrict__ combined,   // [B, H2]
    int* __restrict__ counters)     // [B]
{
    const int b  = blockIdx.y;
    const int hl = threadIdx.x & 31;
    const int h  = blockIdx.x * 32 + hl;
    const int kc = threadIdx.x >> 5;   // 0..7

    if (blockIdx.x == 0 && threadIdx.x == 0)
        counters[b] = 0;               // poison-safe init, once per launch

    __shared__ float sx[H2_];
    __shared__ float zx[TOPIC_];
    for (int i = threadIdx.x; i < H2_; i += 256)    sx[i] = s[b * H2_ + i];
    for (int i = threadIdx.x; i < TOPIC_; i += 256) zx[i] = hz[b * TOPIC_ + i];
    __syncthreads();

    // 4 independent accumulators -> loads pipeline instead of serializing
    float a0 = 0.f, a1 = 0.f, a2 = 0.f, a3 = 0.f;
    {
        const int k0 = kc * 128;                       // 1024 / 8
        const float* Wp = W_s + (size_t)k0 * H2_ + h;
        #pragma unroll 4
        for (int i = 0; i < 128; i += 4) {
            a0 = fmaf(sx[k0 + i    ], Wp[(size_t)(i    ) * H2_], a0);
            a1 = fmaf(sx[k0 + i + 1], Wp[(size_t)(i + 1) * H2_], a1);
            a2 = fmaf(sx[k0 + i + 2], Wp[(size_t)(i + 2) * H2_], a2);
            a3 = fmaf(sx[k0 + i + 3], Wp[(size_t)(i + 3) * H2_], a3);
        }
    }
    {
        const int j0 = kc * 32;                        // 256 / 8
        const float* Wp = W_z + (size_t)j0 * H2_ + h;
        #pragma unroll 4
        for (int i = 0; i < 32; i += 4) {
            a0 = fmaf(zx[j0 + i    ], Wp[(size_t)(i    ) * H2_], a0);
            a1 = fmaf(zx[j0 + i + 1], Wp[(size_t)(i + 1) * H2_], a1);
            a2 = fmaf(zx[j0 + i + 2], Wp[(size_t)(i + 2) * H2_], a2);
            a3 = fmaf(zx[j0 + i + 3], Wp[(size_t)(i + 3) * H2_], a3);
        }
    }
    const float acc = (a0 + a1) + (a2 + a3);

    __shared__ float part[8][32];
    part[kc][hl] = acc;
    __syncthreads();
    if (kc == 0) {
        float r = b_c[h];
        #pragma unroll
        for (int c = 0; c < 8; ++c) r += part[c][hl];
        combined[b * H2_ + h] = r;
    }
}

// Kernel 2: e[row] = sum_h tanh(enc[row][h] + cov[row]*W_c[h] + combined[b][h]) * v[h]
// Wave-per-row (round-5 structure: fastest measured): block = 256 = 4 waves
// = 4 rows, grid = B*S/4 = 8192; 256 blocks per batch.
// Fused softmax: the last block to finish a batch (device-scope counter)
// runs the masked softmax + coverage update for that batch in-kernel.
__global__ __launch_bounds__(256, 4) void et_softmax_kernel(
    const float* __restrict__ enc,       // [B, S, H2]
    const int*   __restrict__ mask,      // [B, S]
    const float* __restrict__ coverage,  // [B, S]
    const float* __restrict__ W_c,       // [H2]
    const float* __restrict__ v,         // [H2]
    const float* __restrict__ combined,  // [B, H2]
    float* __restrict__ e_ws,            // [B, S] scratch
    float* __restrict__ out_a,           // [B, S]
    float* __restrict__ out_cov,         // [B, S]
    int* __restrict__ counters)          // [B], pre-zeroed by kernel 1
{
    const int tid  = threadIdx.x;
    const int row  = blockIdx.x * 4 + (tid >> 6);   // 4 rows per block
    const int b    = row >> 10;                     // S=1024; uniform per block
    const int lane = tid & 63;

    const float4* e4   = (const float4*)enc + (size_t)row * (H2_ / 4);
    const float4* com4 = (const float4*)(combined + (size_t)b * H2_);
    const float4* wc4  = (const float4*)W_c;
    const float4* v4   = (const float4*)v;

    const float cov = coverage[row];

    float acc = 0.0f;
    #pragma unroll
    for (int i = 0; i < 4; ++i) {
        const int idx = lane + i * 64;              // float4 index within row
        const float4 e  = e4[idx];
        const float4 w  = wc4[idx];
        const float4 vv = v4[idx];
        const float4 cb = com4[idx];
        acc = fmaf(fast_tanh(fmaf(cov, w.x, e.x) + cb.x), vv.x, acc);
        acc = fmaf(fast_tanh(fmaf(cov, w.y, e.y) + cb.y), vv.y, acc);
        acc = fmaf(fast_tanh(fmaf(cov, w.z, e.z) + cb.z), vv.z, acc);
        acc = fmaf(fast_tanh(fmaf(cov, w.w, e.w) + cb.w), vv.w, acc);
    }

    #pragma unroll
    for (int off = 32; off > 0; off >>= 1)
        acc += __shfl_xor(acc, off, 64);

    if (lane == 0)
        e_ws[row] = acc;

    // ---- last-block-per-batch fused softmax ----
    __threadfence();          // make this block's e_ws writes device-visible
    __syncthreads();          // all waves' writes precede the arrival below

    __shared__ int is_last;
    if (tid == 0)
        is_last = (atomicAdd(&counters[b], 1) == 255) ? 1 : 0;
    __syncthreads();
    if (!is_last) return;
    __threadfence();          // acquire: other blocks' e_ws writes visible

    float ev[4];
    #pragma unroll
    for (int i = 0; i < 4; ++i) {
        const int idx = b * S_ + tid * 4 + i;
        float e = e_ws[idx];
        if (mask[idx] == 0) e = -INFINITY;
        ev[i] = e;
    }

    float m = fmaxf(fmaxf(ev[0], ev[1]), fmaxf(ev[2], ev[3]));
    #pragma unroll
    for (int off = 1; off < 64; off <<= 1)
        m = fmaxf(m, __shfl_xor(m, off, 64));

    __shared__ float red[4];
    if ((tid & 63) == 0) red[tid >> 6] = m;
    __syncthreads();
    m = fmaxf(fmaxf(red[0], red[1]), fmaxf(red[2], red[3]));

    float p[4];
    float lsum = 0.0f;
    #pragma unroll
    for (int i = 0; i < 4; ++i) {
        p[i] = __expf(ev[i] - m);
        lsum += p[i];
    }
    #pragma unroll
    for (int off = 1; off < 64; off <<= 1)
        lsum += __shfl_xor(lsum, off, 64);

    __syncthreads();          // done reading red[] from max phase
    if ((tid & 63) == 0) red[tid >> 6] = lsum;
    __syncthreads();
    const float tot = red[0] + red[1] + red[2] + red[3];
    const float inv = 1.0f / tot;

    #pragma unroll
    for (int i = 0; i < 4; ++i) {
        const int idx = b * S_ + tid * 4 + i;
        const float a = p[i] * inv;
        out_a[idx]   = a;
        out_cov[idx] = coverage[idx] + a;
    }
}

extern "C" void kernel_launch(void* const* d_in, const int* in_sizes, int n_in,
                              void* d_out, int out_size, void* d_ws, size_t ws_size,
                              hipStream_t stream) {
    const float* enc      = (const float*)d_in[0];
    const int*   mask     = (const int*)  d_in[1];
    const float* s        = (const float*)d_in[2];
    const float* coverage = (const float*)d_in[3];
    const float* hz       = (const float*)d_in[4];
    const float* W_s      = (const float*)d_in[5];
    const float* W_c      = (const float*)d_in[6];
    const float* b_c      = (const float*)d_in[7];
    const float* W_z      = (const float*)d_in[8];
    const float* v        = (const float*)d_in[9];

    float* out_a   = (float*)d_out;            // [B, S]
    float* out_cov = out_a + B_ * S_;          // [B, S]

    float* combined = (float*)d_ws;            // [B, H2]
    float* e_ws     = combined + B_ * H2_;     // [B, S]
    int*   counters = (int*)(e_ws + B_ * S_);  // [B]

    combined_kernel<<<dim3(H2_ / 32, B_), 256, 0, stream>>>(
        s, hz, W_s, W_z, b_c, combined, counters);
    et_softmax_kernel<<<(B_ * S_) / 4, 256, 0, stream>>>(
        enc, mask, coverage, W_c, v, combined, e_ws, out_a, out_cov, counters);
}

// Round 8
// 43.957 us; speedup vs baseline: 18.9501x; 18.9501x over previous
//
#include <hip/hip_runtime.h>
#include <math.h>

#define B_     32
#define S_     1024
#define H2_    1024
#define TOPIC_ 256

typedef float f4 __attribute__((ext_vector_type(4)));

__device__ __forceinline__ float fast_tanh(float x) {
    // tanh(x) = 1 - 2/(exp(2x)+1); saturates to +-1 at extremes.
    float e = __expf(2.0f * x);
    return 1.0f - 2.0f / (e + 1.0f);
}

// Kernel 1: combined[b][h] = sum_k s[b][k]*W_s[k][h] + sum_j hz[b][j]*W_z[j][h] + b_c[h]
// grid = (H2/16, B) = (64, 32) = 2048 blocks, block = 256 (16 k-chunks x 16 h).
// 80 loads/thread, 4 accumulators -> 20 dependent load rounds (vs 40 at 8x32).
__global__ __launch_bounds__(256) void combined_kernel(
    const float* __restrict__ s,    // [B, H2]
    const float* __restrict__ hz,   // [B, TOPIC]
    const float* __restrict__ W_s,  // [H2, H2]  (in, out)
    const float* __restrict__ W_z,  // [TOPIC, H2]
    const float* __restrict__ b_c,  // [H2]
    float* __restrict__ combined)   // [B, H2]
{
    const int b    = blockIdx.y;
    const int hl   = threadIdx.x & 15;
    const int tile = blockIdx.x;
    const int h    = tile * 16 + hl;
    const int kc   = threadIdx.x >> 4;   // 0..15

    __shared__ float sx[H2_];
    __shared__ float zx[TOPIC_];
    for (int i = threadIdx.x; i < H2_; i += 256)    sx[i] = s[b * H2_ + i];
    for (int i = threadIdx.x; i < TOPIC_; i += 256) zx[i] = hz[b * TOPIC_ + i];
    __syncthreads();

    float a0 = 0.f, a1 = 0.f, a2 = 0.f, a3 = 0.f;
    {
        const int k0 = kc * 64;                        // 1024 / 16
        const float* Wp = W_s + (size_t)k0 * H2_ + h;
        #pragma unroll 4
        for (int i = 0; i < 64; i += 4) {
            a0 = fmaf(sx[k0 + i    ], Wp[(size_t)(i    ) * H2_], a0);
            a1 = fmaf(sx[k0 + i + 1], Wp[(size_t)(i + 1) * H2_], a1);
            a2 = fmaf(sx[k0 + i + 2], Wp[(size_t)(i + 2) * H2_], a2);
            a3 = fmaf(sx[k0 + i + 3], Wp[(size_t)(i + 3) * H2_], a3);
        }
    }
    {
        const int j0 = kc * 16;                        // 256 / 16
        const float* Wp = W_z + (size_t)j0 * H2_ + h;
        #pragma unroll 4
        for (int i = 0; i < 16; i += 4) {
            a0 = fmaf(zx[j0 + i    ], Wp[(size_t)(i    ) * H2_], a0);
            a1 = fmaf(zx[j0 + i + 1], Wp[(size_t)(i + 1) * H2_], a1);
            a2 = fmaf(zx[j0 + i + 2], Wp[(size_t)(i + 2) * H2_], a2);
            a3 = fmaf(zx[j0 + i + 3], Wp[(size_t)(i + 3) * H2_], a3);
        }
    }

    __shared__ float part[16][17];   // +1 pad: conflict-free
    part[kc][hl] = (a0 + a1) + (a2 + a3);
    __syncthreads();
    if (threadIdx.x < 16) {
        float r = b_c[tile * 16 + threadIdx.x];
        #pragma unroll
        for (int c = 0; c < 16; ++c) r += part[c][threadIdx.x];
        combined[b * H2_ + tile * 16 + threadIdx.x] = r;
    }
}

// Kernel 2: e[row] = sum_h tanh(enc[row][h] + cov[row]*W_c[h] + combined[b][h]) * v[h]
// 2 rows per wave (8 per block), grid = B*S/8 = 4096 -> same resident-wave
// parallelism as wave-per-row (8 blocks/CU), but hot operands (W_c/v/comb,
// 12 float4) are loaded once per wave and reused for both rows. enc is
// streamed with nontemporal loads (zero reuse -> don't pollute L1).
__global__ __launch_bounds__(256, 4) void et_kernel(
    const float* __restrict__ enc,       // [B, S, H2]
    const float* __restrict__ coverage,  // [B, S]
    const float* __restrict__ W_c,       // [H2]
    const float* __restrict__ v,         // [H2]
    const float* __restrict__ combined,  // [B, H2]
    float* __restrict__ e_out)           // [B, S]
{
    const int tid  = threadIdx.x;
    const int wv   = tid >> 6;
    const int lane = tid & 63;
    const int ra   = blockIdx.x * 8 + wv * 2;    // 2 rows per wave
    const int rb   = ra + 1;
    const int b    = ra >> 10;                   // S = 1024, uniform per block

    const f4* com4 = (const f4*)(combined + (size_t)b * H2_);
    const f4* wc4  = (const f4*)W_c;
    const f4* v4   = (const f4*)v;
    const f4* ea   = (const f4*)enc + (size_t)ra * (H2_ / 4);
    const f4* eb   = (const f4*)enc + (size_t)rb * (H2_ / 4);

    // Hot per-wave invariants: 12 float4 = 48 VGPR.
    f4 wc[4], vv[4], cb[4];
    #pragma unroll
    for (int i = 0; i < 4; ++i) {
        const int idx = lane + i * 64;
        wc[i] = wc4[idx];
        vv[i] = v4[idx];
        cb[i] = com4[idx];
    }

    const float cva = coverage[ra];
    const float cvb = coverage[rb];

    f4 La[4], Lb[4];
    #pragma unroll
    for (int i = 0; i < 4; ++i) {
        La[i] = __builtin_nontemporal_load(&ea[lane + i * 64]);
        Lb[i] = __builtin_nontemporal_load(&eb[lane + i * 64]);
    }

    float aca = 0.0f, acb = 0.0f;
    #pragma unroll
    for (int i = 0; i < 4; ++i) {
        aca = fmaf(fast_tanh(fmaf(cva, wc[i].x, La[i].x + cb[i].x)), vv[i].x, aca);
        aca = fmaf(fast_tanh(fmaf(cva, wc[i].y, La[i].y + cb[i].y)), vv[i].y, aca);
        aca = fmaf(fast_tanh(fmaf(cva, wc[i].z, La[i].z + cb[i].z)), vv[i].z, aca);
        aca = fmaf(fast_tanh(fmaf(cva, wc[i].w, La[i].w + cb[i].w)), vv[i].w, aca);
        acb = fmaf(fast_tanh(fmaf(cvb, wc[i].x, Lb[i].x + cb[i].x)), vv[i].x, acb);
        acb = fmaf(fast_tanh(fmaf(cvb, wc[i].y, Lb[i].y + cb[i].y)), vv[i].y, acb);
        acb = fmaf(fast_tanh(fmaf(cvb, wc[i].z, Lb[i].z + cb[i].z)), vv[i].z, acb);
        acb = fmaf(fast_tanh(fmaf(cvb, wc[i].w, Lb[i].w + cb[i].w)), vv[i].w, acb);
    }

    #pragma unroll
    for (int off = 32; off > 0; off >>= 1) {
        aca += __shfl_xor(aca, off, 64);
        acb += __shfl_xor(acb, off, 64);
    }
    if (lane == 0) {
        e_out[ra] = aca;
        e_out[rb] = acb;
    }
}

// Kernel 3: masked softmax over S per batch + next_coverage.
// Single-pass (no max subtraction): |e| <= ||v||_1 ~ 26 since |tanh|<=1,
// so exp(e) <= ~1e13 and the fp32 sum is safe; masked lanes contribute 0.
// grid = B, block = 256 (4 elems per thread)
__global__ __launch_bounds__(256) void softmax_kernel(
    const float* __restrict__ e_in,      // [B, S]
    const int*   __restrict__ mask,      // [B, S]
    const float* __restrict__ coverage,  // [B, S]
    float* __restrict__ a_out,           // [B, S]
    float* __restrict__ cov_out)         // [B, S]
{
    const int b   = blockIdx.x;
    const int tid = threadIdx.x;

    float p[4];
    float lsum = 0.0f;
    #pragma unroll
    for (int i = 0; i < 4; ++i) {
        const int idx = b * S_ + tid * 4 + i;
        p[i] = (mask[idx] == 0) ? 0.0f : __expf(e_in[idx]);
        lsum += p[i];
    }
    #pragma unroll
    for (int off = 1; off < 64; off <<= 1)
        lsum += __shfl_xor(lsum, off, 64);

    __shared__ float red[4];
    if ((tid & 63) == 0) red[tid >> 6] = lsum;
    __syncthreads();
    const float tot = red[0] + red[1] + red[2] + red[3];
    const float inv = 1.0f / tot;

    #pragma unroll
    for (int i = 0; i < 4; ++i) {
        const int idx = b * S_ + tid * 4 + i;
        const float a = p[i] * inv;
        a_out[idx]   = a;
        cov_out[idx] = coverage[idx] + a;
    }
}

extern "C" void kernel_launch(void* const* d_in, const int* in_sizes, int n_in,
                              void* d_out, int out_size, void* d_ws, size_t ws_size,
                              hipStream_t stream) {
    const float* enc      = (const float*)d_in[0];
    const int*   mask     = (const int*)  d_in[1];
    const float* s        = (const float*)d_in[2];
    const float* coverage = (const float*)d_in[3];
    const float* hz       = (const float*)d_in[4];
    const float* W_s      = (const float*)d_in[5];
    const float* W_c      = (const float*)d_in[6];
    const float* b_c      = (const float*)d_in[7];
    const float* W_z      = (const float*)d_in[8];
    const float* v        = (const float*)d_in[9];

    float* out_a   = (float*)d_out;            // [B, S]
    float* out_cov = out_a + B_ * S_;          // [B, S]

    float* combined = (float*)d_ws;            // [B, H2]
    float* e_ws     = combined + B_ * H2_;     // [B, S]

    combined_kernel<<<dim3(H2_ / 16, B_), 256, 0, stream>>>(s, hz, W_s, W_z, b_c, combined);
    et_kernel<<<(B_ * S_) / 8, 256, 0, stream>>>(enc, coverage, W_c, v, combined, e_ws);
    softmax_kernel<<<B_, 256, 0, stream>>>(e_ws, mask, coverage, out_a, out_cov);
}

// Round 9
// 42.775 us; speedup vs baseline: 19.4739x; 1.0276x over previous
//
#include <hip/hip_runtime.h>
#include <math.h>

#define B_     32
#define S_     1024
#define H2_    1024
#define TOPIC_ 256

typedef float f4 __attribute__((ext_vector_type(4)));

__device__ __forceinline__ float fast_tanh(float x) {
    // tanh(x) = 1 - 2/(exp(2x)+1); saturates to +-1 at extremes.
    float e = __expf(2.0f * x);
    return 1.0f - 2.0f / (e + 1.0f);
}

// Kernel 1: combined[b][h] = sum_k s[b][k]*W_s[k][h] + sum_j hz[b][j]*W_z[j][h] + b_c[h]
// grid = (H2/16, B) = (64, 32) = 2048 blocks, block = 256 (16 k-chunks x 16 h).
// 80 loads/thread, 4 accumulators -> 20 dependent load rounds.
__global__ __launch_bounds__(256) void combined_kernel(
    const float* __restrict__ s,    // [B, H2]
    const float* __restrict__ hz,   // [B, TOPIC]
    const float* __restrict__ W_s,  // [H2, H2]  (in, out)
    const float* __restrict__ W_z,  // [TOPIC, H2]
    const float* __restrict__ b_c,  // [H2]
    float* __restrict__ combined)   // [B, H2]
{
    const int b    = blockIdx.y;
    const int hl   = threadIdx.x & 15;
    const int tile = blockIdx.x;
    const int h    = tile * 16 + hl;
    const int kc   = threadIdx.x >> 4;   // 0..15

    __shared__ float sx[H2_];
    __shared__ float zx[TOPIC_];
    for (int i = threadIdx.x; i < H2_; i += 256)    sx[i] = s[b * H2_ + i];
    for (int i = threadIdx.x; i < TOPIC_; i += 256) zx[i] = hz[b * TOPIC_ + i];
    __syncthreads();

    float a0 = 0.f, a1 = 0.f, a2 = 0.f, a3 = 0.f;
    {
        const int k0 = kc * 64;                        // 1024 / 16
        const float* Wp = W_s + (size_t)k0 * H2_ + h;
        #pragma unroll 4
        for (int i = 0; i < 64; i += 4) {
            a0 = fmaf(sx[k0 + i    ], Wp[(size_t)(i    ) * H2_], a0);
            a1 = fmaf(sx[k0 + i + 1], Wp[(size_t)(i + 1) * H2_], a1);
            a2 = fmaf(sx[k0 + i + 2], Wp[(size_t)(i + 2) * H2_], a2);
            a3 = fmaf(sx[k0 + i + 3], Wp[(size_t)(i + 3) * H2_], a3);
        }
    }
    {
        const int j0 = kc * 16;                        // 256 / 16
        const float* Wp = W_z + (size_t)j0 * H2_ + h;
        #pragma unroll 4
        for (int i = 0; i < 16; i += 4) {
            a0 = fmaf(zx[j0 + i    ], Wp[(size_t)(i    ) * H2_], a0);
            a1 = fmaf(zx[j0 + i + 1], Wp[(size_t)(i + 1) * H2_], a1);
            a2 = fmaf(zx[j0 + i + 2], Wp[(size_t)(i + 2) * H2_], a2);
            a3 = fmaf(zx[j0 + i + 3], Wp[(size_t)(i + 3) * H2_], a3);
        }
    }

    __shared__ float part[16][17];   // +1 pad: conflict-free
    part[kc][hl] = (a0 + a1) + (a2 + a3);
    __syncthreads();
    if (threadIdx.x < 16) {
        float r = b_c[tile * 16 + threadIdx.x];
        #pragma unroll
        for (int c = 0; c < 16; ++c) r += part[c][threadIdx.x];
        combined[b * H2_ + tile * 16 + threadIdx.x] = r;
    }
}

// Kernel 2: e[row] = sum_h tanh(enc[row][h] + cov[row]*W_c[h] + combined[b][h]) * v[h]
// Wave-per-row (round-5 proven structure), PLAIN loads (keep L3 warmth --
// round 8's nontemporal loads forfeited ~64 MB of L3 hits and regressed).
// block = 256 = 4 waves = 4 rows, grid = B*S/4 = 8192.
// (256, 8): body measured at 28 VGPR (round 7) -> fits the 64-VGPR cap,
// doubling resident waves to 32/CU for latency hiding.
__global__ __launch_bounds__(256, 8) void et_kernel(
    const float* __restrict__ enc,       // [B, S, H2]
    const float* __restrict__ coverage,  // [B, S]
    const float* __restrict__ W_c,       // [H2]
    const float* __restrict__ v,         // [H2]
    const float* __restrict__ combined,  // [B, H2]
    float* __restrict__ e_out)           // [B, S]
{
    const int tid  = threadIdx.x;
    const int row  = blockIdx.x * 4 + (tid >> 6);   // 4 rows per block
    const int b    = row >> 10;                     // S = 1024
    const int lane = tid & 63;

    const f4* e4   = (const f4*)enc + (size_t)row * (H2_ / 4);
    const f4* com4 = (const f4*)(combined + (size_t)b * H2_);
    const f4* wc4  = (const f4*)W_c;
    const f4* v4   = (const f4*)v;

    const float cov = coverage[row];

    float acc = 0.0f;
    #pragma unroll
    for (int i = 0; i < 4; ++i) {
        const int idx = lane + i * 64;              // float4 index within row
        const f4 e  = e4[idx];
        const f4 w  = wc4[idx];
        const f4 vv = v4[idx];
        const f4 cb = com4[idx];
        acc = fmaf(fast_tanh(fmaf(cov, w.x, e.x) + cb.x), vv.x, acc);
        acc = fmaf(fast_tanh(fmaf(cov, w.y, e.y) + cb.y), vv.y, acc);
        acc = fmaf(fast_tanh(fmaf(cov, w.z, e.z) + cb.z), vv.z, acc);
        acc = fmaf(fast_tanh(fmaf(cov, w.w, e.w) + cb.w), vv.w, acc);
    }

    #pragma unroll
    for (int off = 32; off > 0; off >>= 1)
        acc += __shfl_xor(acc, off, 64);

    if (lane == 0)
        e_out[row] = acc;
}

// Kernel 3: masked softmax over S per batch + next_coverage.
// Single-pass (no max subtraction): |e| <= ||v||_1 ~ 26 since |tanh|<=1,
// so exp(e) is finite-safe in fp32; masked lanes contribute exactly 0.
// grid = B, block = 256 (4 elems per thread)
__global__ __launch_bounds__(256) void softmax_kernel(
    const float* __restrict__ e_in,      // [B, S]
    const int*   __restrict__ mask,      // [B, S]
    const float* __restrict__ coverage,  // [B, S]
    float* __restrict__ a_out,           // [B, S]
    float* __restrict__ cov_out)         // [B, S]
{
    const int b   = blockIdx.x;
    const int tid = threadIdx.x;

    float p[4];
    float lsum = 0.0f;
    #pragma unroll
    for (int i = 0; i < 4; ++i) {
        const int idx = b * S_ + tid * 4 + i;
        p[i] = (mask[idx] == 0) ? 0.0f : __expf(e_in[idx]);
        lsum += p[i];
    }
    #pragma unroll
    for (int off = 1; off < 64; off <<= 1)
        lsum += __shfl_xor(lsum, off, 64);

    __shared__ float red[4];
    if ((tid & 63) == 0) red[tid >> 6] = lsum;
    __syncthreads();
    const float tot = red[0] + red[1] + red[2] + red[3];
    const float inv = 1.0f / tot;

    #pragma unroll
    for (int i = 0; i < 4; ++i) {
        const int idx = b * S_ + tid * 4 + i;
        const float a = p[i] * inv;
        a_out[idx]   = a;
        cov_out[idx] = coverage[idx] + a;
    }
}

extern "C" void kernel_launch(void* const* d_in, const int* in_sizes, int n_in,
                              void* d_out, int out_size, void* d_ws, size_t ws_size,
                              hipStream_t stream) {
    const float* enc      = (const float*)d_in[0];
    const int*   mask     = (const int*)  d_in[1];
    const float* s        = (const float*)d_in[2];
    const float* coverage = (const float*)d_in[3];
    const float* hz       = (const float*)d_in[4];
    const float* W_s      = (const float*)d_in[5];
    const float* W_c      = (const float*)d_in[6];
    const float* b_c      = (const float*)d_in[7];
    const float* W_z      = (const float*)d_in[8];
    const float* v        = (const float*)d_in[9];

    float* out_a   = (float*)d_out;            // [B, S]
    float* out_cov = out_a + B_ * S_;          // [B, S]

    float* combined = (float*)d_ws;            // [B, H2]
    float* e_ws     = combined + B_ * H2_;     // [B, S]

    combined_kernel<<<dim3(H2_ / 16, B_), 256, 0, stream>>>(s, hz, W_s, W_z, b_c, combined);
    et_kernel<<<(B_ * S_) / 4, 256, 0, stream>>>(enc, coverage, W_c, v, combined, e_ws);
    softmax_kernel<<<B_, 256, 0, stream>>>(e_ws, mask, coverage, out_a, out_cov);
}

// Round 10
// 39.468 us; speedup vs baseline: 21.1054x; 1.0838x over previous
//
#include <hip/hip_runtime.h>
#include <math.h>

#define B_     32
#define S_     1024
#define H2_    1024
#define TOPIC_ 256

typedef float f4 __attribute__((ext_vector_type(4)));

__device__ __forceinline__ float fast_tanh(float x) {
    // tanh(x) = 1 - 2/(exp(2x)+1); saturates to +-1 at extremes.
    float e = __expf(2.0f * x);
    return 1.0f - 2.0f / (e + 1.0f);
}

// Kernel 1: combined[b][h] = sum_k s[b][k]*W_s[k][h] + sum_j hz[b][j]*W_z[j][h] + b_c[h]
// grid = (H2/32, B) = (32, 32), block = 256 (8 k-chunks x 32 h) -- round-5
// proven config (38.5 us wall).
__global__ __launch_bounds__(256) void combined_kernel(
    const float* __restrict__ s,    // [B, H2]
    const float* __restrict__ hz,   // [B, TOPIC]
    const float* __restrict__ W_s,  // [H2, H2]  (in, out)
    const float* __restrict__ W_z,  // [TOPIC, H2]
    const float* __restrict__ b_c,  // [H2]
    float* __restrict__ combined)   // [B, H2]
{
    const int b  = blockIdx.y;
    const int hl = threadIdx.x & 31;
    const int h  = blockIdx.x * 32 + hl;
    const int kc = threadIdx.x >> 5;   // 0..7

    __shared__ float sx[H2_];
    __shared__ float zx[TOPIC_];
    for (int i = threadIdx.x; i < H2_; i += 256)    sx[i] = s[b * H2_ + i];
    for (int i = threadIdx.x; i < TOPIC_; i += 256) zx[i] = hz[b * TOPIC_ + i];
    __syncthreads();

    // 4 independent accumulators -> loads pipeline instead of serializing
    float a0 = 0.f, a1 = 0.f, a2 = 0.f, a3 = 0.f;
    {
        const int k0 = kc * 128;                       // 1024 / 8
        const float* Wp = W_s + (size_t)k0 * H2_ + h;
        #pragma unroll 4
        for (int i = 0; i < 128; i += 4) {
            a0 = fmaf(sx[k0 + i    ], Wp[(size_t)(i    ) * H2_], a0);
            a1 = fmaf(sx[k0 + i + 1], Wp[(size_t)(i + 1) * H2_], a1);
            a2 = fmaf(sx[k0 + i + 2], Wp[(size_t)(i + 2) * H2_], a2);
            a3 = fmaf(sx[k0 + i + 3], Wp[(size_t)(i + 3) * H2_], a3);
        }
    }
    {
        const int j0 = kc * 32;                        // 256 / 8
        const float* Wp = W_z + (size_t)j0 * H2_ + h;
        #pragma unroll 4
        for (int i = 0; i < 32; i += 4) {
            a0 = fmaf(zx[j0 + i    ], Wp[(size_t)(i    ) * H2_], a0);
            a1 = fmaf(zx[j0 + i + 1], Wp[(size_t)(i + 1) * H2_], a1);
            a2 = fmaf(zx[j0 + i + 2], Wp[(size_t)(i + 2) * H2_], a2);
            a3 = fmaf(zx[j0 + i + 3], Wp[(size_t)(i + 3) * H2_], a3);
        }
    }
    const float acc = (a0 + a1) + (a2 + a3);

    __shared__ float part[8][32];
    part[kc][hl] = acc;
    __syncthreads();
    if (kc == 0) {
        float r = b_c[h];
        #pragma unroll
        for (int c = 0; c < 8; ++c) r += part[c][hl];
        combined[b * H2_ + h] = r;
    }
}

// Kernel 2: e[row] = sum_h tanh(enc[row][h] + cov[row]*W_c[h] + combined[b][h]) * v[h]
// Wave-per-row, round-5 EXACT structure: block = 256 = 4 waves = 4 rows,
// grid = B*S/4 = 8192, (256,4) -> 128-VGPR budget keeps all 16 float4 loads
// in flight (round 9's (256,8)/64-VGPR cap halved MLP and regressed).
__global__ __launch_bounds__(256, 4) void et_kernel(
    const float* __restrict__ enc,       // [B, S, H2]
    const float* __restrict__ coverage,  // [B, S]
    const float* __restrict__ W_c,       // [H2]
    const float* __restrict__ v,         // [H2]
    const float* __restrict__ combined,  // [B, H2]
    float* __restrict__ e_out)           // [B, S]
{
    const int tid  = threadIdx.x;
    const int row  = blockIdx.x * 4 + (tid >> 6);   // 4 rows per block
    const int b    = row >> 10;                     // S = 1024
    const int lane = tid & 63;

    const f4* e4   = (const f4*)enc + (size_t)row * (H2_ / 4);
    const f4* com4 = (const f4*)(combined + (size_t)b * H2_);
    const f4* wc4  = (const f4*)W_c;
    const f4* v4   = (const f4*)v;

    const float cov = coverage[row];

    float acc = 0.0f;
    #pragma unroll
    for (int i = 0; i < 4; ++i) {
        const int idx = lane + i * 64;              // float4 index within row
        const f4 e  = e4[idx];
        const f4 w  = wc4[idx];
        const f4 vv = v4[idx];
        const f4 cb = com4[idx];
        acc = fmaf(fast_tanh(fmaf(cov, w.x, e.x) + cb.x), vv.x, acc);
        acc = fmaf(fast_tanh(fmaf(cov, w.y, e.y) + cb.y), vv.y, acc);
        acc = fmaf(fast_tanh(fmaf(cov, w.z, e.z) + cb.z), vv.z, acc);
        acc = fmaf(fast_tanh(fmaf(cov, w.w, e.w) + cb.w), vv.w, acc);
    }

    #pragma unroll
    for (int off = 32; off > 0; off >>= 1)
        acc += __shfl_xor(acc, off, 64);

    if (lane == 0)
        e_out[row] = acc;
}

// Kernel 3: masked softmax over S per batch + next_coverage.
// Single-pass (no max subtraction): |e| <= ||v||_1 ~ 26 since |tanh|<=1,
// so exp(e) is finite-safe in fp32; masked lanes contribute exactly 0.
// grid = B, block = 256 (4 elems per thread)
__global__ __launch_bounds__(256) void softmax_kernel(
    const float* __restrict__ e_in,      // [B, S]
    const int*   __restrict__ mask,      // [B, S]
    const float* __restrict__ coverage,  // [B, S]
    float* __restrict__ a_out,           // [B, S]
    float* __restrict__ cov_out)         // [B, S]
{
    const int b   = blockIdx.x;
    const int tid = threadIdx.x;

    float p[4];
    float lsum = 0.0f;
    #pragma unroll
    for (int i = 0; i < 4; ++i) {
        const int idx = b * S_ + tid * 4 + i;
        p[i] = (mask[idx] == 0) ? 0.0f : __expf(e_in[idx]);
        lsum += p[i];
    }
    #pragma unroll
    for (int off = 1; off < 64; off <<= 1)
        lsum += __shfl_xor(lsum, off, 64);

    __shared__ float red[4];
    if ((tid & 63) == 0) red[tid >> 6] = lsum;
    __syncthreads();
    const float tot = red[0] + red[1] + red[2] + red[3];
    const float inv = 1.0f / tot;

    #pragma unroll
    for (int i = 0; i < 4; ++i) {
        const int idx = b * S_ + tid * 4 + i;
        const float a = p[i] * inv;
        a_out[idx]   = a;
        cov_out[idx] = coverage[idx] + a;
    }
}

extern "C" void kernel_launch(void* const* d_in, const int* in_sizes, int n_in,
                              void* d_out, int out_size, void* d_ws, size_t ws_size,
                              hipStream_t stream) {
    const float* enc      = (const float*)d_in[0];
    const int*   mask     = (const int*)  d_in[1];
    const float* s        = (const float*)d_in[2];
    const float* coverage = (const float*)d_in[3];
    const float* hz       = (const float*)d_in[4];
    const float* W_s      = (const float*)d_in[5];
    const float* W_c      = (const float*)d_in[6];
    const float* b_c      = (const float*)d_in[7];
    const float* W_z      = (const float*)d_in[8];
    const float* v        = (const float*)d_in[9];

    float* out_a   = (float*)d_out;            // [B, S]
    float* out_cov = out_a + B_ * S_;          // [B, S]

    float* combined = (float*)d_ws;            // [B, H2]
    float* e_ws     = combined + B_ * H2_;     // [B, S]

    combined_kernel<<<dim3(H2_ / 32, B_), 256, 0, stream>>>(s, hz, W_s, W_z, b_c, combined);
    et_kernel<<<(B_ * S_) / 4, 256, 0, stream>>>(enc, coverage, W_c, v, combined, e_ws);
    softmax_kernel<<<B_, 256, 0, stream>>>(e_ws, mask, coverage, out_a, out_cov);
}

// Round 11
// 38.125 us; speedup vs baseline: 21.8491x; 1.0352x over previous
//
#include <hip/hip_runtime.h>
#include <math.h>

#define B_     32
#define S_     1024
#define H2_    1024
#define TOPIC_ 256

typedef float f4 __attribute__((ext_vector_type(4)));

__device__ __forceinline__ float fast_tanh(float x) {
    // tanh(x) = 1 - 2/(exp(2x)+1); saturates to +-1 at extremes.
    float e = __expf(2.0f * x);
    return 1.0f - 2.0f / (e + 1.0f);
}

// Kernel 1: combined[b][h] = sum_k s[b][k]*W_s[k][h] + sum_j hz[b][j]*W_z[j][h] + b_c[h]
// grid = (H2/32, B) = (32, 32), block = 256 (8 k-chunks x 32 h).
// 8 independent accumulators: 160 loads/thread -> 20 dependent load rounds
// (was 40 with 4 acc); each round ~L2 latency, so chain time halves.
__global__ __launch_bounds__(256) void combined_kernel(
    const float* __restrict__ s,    // [B, H2]
    const float* __restrict__ hz,   // [B, TOPIC]
    const float* __restrict__ W_s,  // [H2, H2]  (in, out)
    const float* __restrict__ W_z,  // [TOPIC, H2]
    const float* __restrict__ b_c,  // [H2]
    float* __restrict__ combined)   // [B, H2]
{
    const int b  = blockIdx.y;
    const int hl = threadIdx.x & 31;
    const int h  = blockIdx.x * 32 + hl;
    const int kc = threadIdx.x >> 5;   // 0..7

    __shared__ float sx[H2_];
    __shared__ float zx[TOPIC_];
    for (int i = threadIdx.x; i < H2_; i += 256)    sx[i] = s[b * H2_ + i];
    for (int i = threadIdx.x; i < TOPIC_; i += 256) zx[i] = hz[b * TOPIC_ + i];
    __syncthreads();

    float a0 = 0.f, a1 = 0.f, a2 = 0.f, a3 = 0.f;
    float a4 = 0.f, a5 = 0.f, a6 = 0.f, a7 = 0.f;
    {
        const int k0 = kc * 128;                       // 1024 / 8
        const float* Wp = W_s + (size_t)k0 * H2_ + h;
        #pragma unroll 2
        for (int i = 0; i < 128; i += 8) {
            a0 = fmaf(sx[k0 + i    ], Wp[(size_t)(i    ) * H2_], a0);
            a1 = fmaf(sx[k0 + i + 1], Wp[(size_t)(i + 1) * H2_], a1);
            a2 = fmaf(sx[k0 + i + 2], Wp[(size_t)(i + 2) * H2_], a2);
            a3 = fmaf(sx[k0 + i + 3], Wp[(size_t)(i + 3) * H2_], a3);
            a4 = fmaf(sx[k0 + i + 4], Wp[(size_t)(i + 4) * H2_], a4);
            a5 = fmaf(sx[k0 + i + 5], Wp[(size_t)(i + 5) * H2_], a5);
            a6 = fmaf(sx[k0 + i + 6], Wp[(size_t)(i + 6) * H2_], a6);
            a7 = fmaf(sx[k0 + i + 7], Wp[(size_t)(i + 7) * H2_], a7);
        }
    }
    {
        const int j0 = kc * 32;                        // 256 / 8
        const float* Wp = W_z + (size_t)j0 * H2_ + h;
        #pragma unroll
        for (int i = 0; i < 32; i += 8) {
            a0 = fmaf(zx[j0 + i    ], Wp[(size_t)(i    ) * H2_], a0);
            a1 = fmaf(zx[j0 + i + 1], Wp[(size_t)(i + 1) * H2_], a1);
            a2 = fmaf(zx[j0 + i + 2], Wp[(size_t)(i + 2) * H2_], a2);
            a3 = fmaf(zx[j0 + i + 3], Wp[(size_t)(i + 3) * H2_], a3);
            a4 = fmaf(zx[j0 + i + 4], Wp[(size_t)(i + 4) * H2_], a4);
            a5 = fmaf(zx[j0 + i + 5], Wp[(size_t)(i + 5) * H2_], a5);
            a6 = fmaf(zx[j0 + i + 6], Wp[(size_t)(i + 6) * H2_], a6);
            a7 = fmaf(zx[j0 + i + 7], Wp[(size_t)(i + 7) * H2_], a7);
        }
    }
    const float acc = ((a0 + a1) + (a2 + a3)) + ((a4 + a5) + (a6 + a7));

    __shared__ float part[8][32];
    part[kc][hl] = acc;
    __syncthreads();
    if (kc == 0) {
        float r = b_c[h];
        #pragma unroll
        for (int c = 0; c < 8; ++c) r += part[c][hl];
        combined[b * H2_ + h] = r;
    }
}

// Kernel 2: e[row] = sum_h tanh(enc[row][h] + cov[row]*W_c[h] + combined[b][h]) * v[h]
// Wave-per-row, round-5 EXACT structure (proven fastest): block = 256 =
// 4 waves = 4 rows, grid = B*S/4 = 8192, (256,4) -> 128-VGPR budget keeps
// all 16 float4 loads in flight.
__global__ __launch_bounds__(256, 4) void et_kernel(
    const float* __restrict__ enc,       // [B, S, H2]
    const float* __restrict__ coverage,  // [B, S]
    const float* __restrict__ W_c,       // [H2]
    const float* __restrict__ v,         // [H2]
    const float* __restrict__ combined,  // [B, H2]
    float* __restrict__ e_out)           // [B, S]
{
    const int tid  = threadIdx.x;
    const int row  = blockIdx.x * 4 + (tid >> 6);   // 4 rows per block
    const int b    = row >> 10;                     // S = 1024
    const int lane = tid & 63;

    const f4* e4   = (const f4*)enc + (size_t)row * (H2_ / 4);
    const f4* com4 = (const f4*)(combined + (size_t)b * H2_);
    const f4* wc4  = (const f4*)W_c;
    const f4* v4   = (const f4*)v;

    const float cov = coverage[row];

    float acc = 0.0f;
    #pragma unroll
    for (int i = 0; i < 4; ++i) {
        const int idx = lane + i * 64;              // float4 index within row
        const f4 e  = e4[idx];
        const f4 w  = wc4[idx];
        const f4 vv = v4[idx];
        const f4 cb = com4[idx];
        acc = fmaf(fast_tanh(fmaf(cov, w.x, e.x) + cb.x), vv.x, acc);
        acc = fmaf(fast_tanh(fmaf(cov, w.y, e.y) + cb.y), vv.y, acc);
        acc = fmaf(fast_tanh(fmaf(cov, w.z, e.z) + cb.z), vv.z, acc);
        acc = fmaf(fast_tanh(fmaf(cov, w.w, e.w) + cb.w), vv.w, acc);
    }

    #pragma unroll
    for (int off = 32; off > 0; off >>= 1)
        acc += __shfl_xor(acc, off, 64);

    if (lane == 0)
        e_out[row] = acc;
}

// Kernel 3: masked softmax over S per batch + next_coverage.
// Single-pass (no max subtraction): |e| <= ||v||_1 ~ 26 since |tanh|<=1,
// so exp(e) is finite-safe in fp32; masked lanes contribute exactly 0.
// Vectorized f4/int4 loads and f4 stores.
// grid = B, block = 256 (4 elems per thread)
__global__ __launch_bounds__(256) void softmax_kernel(
    const float* __restrict__ e_in,      // [B, S]
    const int*   __restrict__ mask,      // [B, S]
    const float* __restrict__ coverage,  // [B, S]
    float* __restrict__ a_out,           // [B, S]
    float* __restrict__ cov_out)         // [B, S]
{
    const int b   = blockIdx.x;
    const int tid = threadIdx.x;

    const f4  ev = ((const f4*)(e_in + b * S_))[tid];
    const int4 mk = ((const int4*)(mask + b * S_))[tid];
    const f4  cv = ((const f4*)(coverage + b * S_))[tid];

    f4 p;
    p.x = (mk.x == 0) ? 0.0f : __expf(ev.x);
    p.y = (mk.y == 0) ? 0.0f : __expf(ev.y);
    p.z = (mk.z == 0) ? 0.0f : __expf(ev.z);
    p.w = (mk.w == 0) ? 0.0f : __expf(ev.w);

    float lsum = (p.x + p.y) + (p.z + p.w);
    #pragma unroll
    for (int off = 1; off < 64; off <<= 1)
        lsum += __shfl_xor(lsum, off, 64);

    __shared__ float red[4];
    if ((tid & 63) == 0) red[tid >> 6] = lsum;
    __syncthreads();
    const float tot = red[0] + red[1] + red[2] + red[3];
    const float inv = 1.0f / tot;

    f4 a, nc;
    a.x = p.x * inv;  a.y = p.y * inv;  a.z = p.z * inv;  a.w = p.w * inv;
    nc.x = cv.x + a.x; nc.y = cv.y + a.y; nc.z = cv.z + a.z; nc.w = cv.w + a.w;

    ((f4*)(a_out   + b * S_))[tid] = a;
    ((f4*)(cov_out + b * S_))[tid] = nc;
}

extern "C" void kernel_launch(void* const* d_in, const int* in_sizes, int n_in,
                              void* d_out, int out_size, void* d_ws, size_t ws_size,
                              hipStream_t stream) {
    const float* enc      = (const float*)d_in[0];
    const int*   mask     = (const int*)  d_in[1];
    const float* s        = (const float*)d_in[2];
    const float* coverage = (const float*)d_in[3];
    const float* hz       = (const float*)d_in[4];
    const float* W_s      = (const float*)d_in[5];
    const float* W_c      = (const float*)d_in[6];
    const float* b_c      = (const float*)d_in[7];
    const float* W_z      = (const float*)d_in[8];
    const float* v        = (const float*)d_in[9];

    float* out_a   = (float*)d_out;            // [B, S]
    float* out_cov = out_a + B_ * S_;          // [B, S]

    float* combined = (float*)d_ws;            // [B, H2]
    float* e_ws     = combined + B_ * H2_;     // [B, S]

    combined_kernel<<<dim3(H2_ / 32, B_), 256, 0, stream>>>(s, hz, W_s, W_z, b_c, combined);
    et_kernel<<<(B_ * S_) / 4, 256, 0, stream>>>(enc, coverage, W_c, v, combined, e_ws);
    softmax_kernel<<<B_, 256, 0, stream>>>(e_ws, mask, coverage, out_a, out_cov);
}

// Round 12
// 37.511 us; speedup vs baseline: 22.2068x; 1.0164x over previous
//
#include <hip/hip_runtime.h>
#include <math.h>

#define B_     32
#define S_     1024
#define H2_    1024
#define TOPIC_ 256

typedef float f4 __attribute__((ext_vector_type(4)));

__device__ __forceinline__ float fast_tanh(float x) {
    // tanh(x) = 1 - 2/(exp(2x)+1); saturates to +-1 at extremes.
    float e = __expf(2.0f * x);
    return 1.0f - 2.0f / (e + 1.0f);
}

// Kernel 1: combined[b][h] = sum_k s[b][k]*W_s[k][h] + sum_j hz[b][j]*W_z[j][h] + b_c[h]
// grid = (H2/32, B) = (32, 32), block = 256 (8 k-chunks x 32 h).
// 16 independent accumulators: 160 loads/thread -> 10 dependent load rounds
// (r10: 4 acc/40 rounds; r11: 8 acc/20 rounds -> measured win; this: 10).
__global__ __launch_bounds__(256) void combined_kernel(
    const float* __restrict__ s,    // [B, H2]
    const float* __restrict__ hz,   // [B, TOPIC]
    const float* __restrict__ W_s,  // [H2, H2]  (in, out)
    const float* __restrict__ W_z,  // [TOPIC, H2]
    const float* __restrict__ b_c,  // [H2]
    float* __restrict__ combined)   // [B, H2]
{
    const int b  = blockIdx.y;
    const int hl = threadIdx.x & 31;
    const int h  = blockIdx.x * 32 + hl;
    const int kc = threadIdx.x >> 5;   // 0..7

    __shared__ float sx[H2_];
    __shared__ float zx[TOPIC_];
    for (int i = threadIdx.x; i < H2_; i += 256)    sx[i] = s[b * H2_ + i];
    for (int i = threadIdx.x; i < TOPIC_; i += 256) zx[i] = hz[b * TOPIC_ + i];
    __syncthreads();

    float a[16];
    #pragma unroll
    for (int u = 0; u < 16; ++u) a[u] = 0.0f;
    {
        const int k0 = kc * 128;                       // 1024 / 8
        const float* Wp = W_s + (size_t)k0 * H2_ + h;
        #pragma unroll
        for (int i = 0; i < 128; i += 16) {
            #pragma unroll
            for (int u = 0; u < 16; ++u)
                a[u] = fmaf(sx[k0 + i + u], Wp[(size_t)(i + u) * H2_], a[u]);
        }
    }
    {
        const int j0 = kc * 32;                        // 256 / 8
        const float* Wp = W_z + (size_t)j0 * H2_ + h;
        #pragma unroll
        for (int i = 0; i < 32; i += 16) {
            #pragma unroll
            for (int u = 0; u < 16; ++u)
                a[u] = fmaf(zx[j0 + i + u], Wp[(size_t)(i + u) * H2_], a[u]);
        }
    }
    float acc = 0.0f;
    #pragma unroll
    for (int u = 0; u < 16; ++u) acc += a[u];

    __shared__ float part[8][32];
    part[kc][hl] = acc;
    __syncthreads();
    if (kc == 0) {
        float r = b_c[h];
        #pragma unroll
        for (int c = 0; c < 8; ++c) r += part[c][hl];
        combined[b * H2_ + h] = r;
    }
}

// Kernel 2: e[row] = sum_h tanh(enc[row][h] + cov[row]*W_c[h] + combined[b][h]) * v[h]
// Wave-per-row, round-5 EXACT structure (proven fastest; ~89% of HBM
// roofline): block = 256 = 4 waves = 4 rows, grid = B*S/4 = 8192, (256,4)
// -> 128-VGPR budget keeps all 16 float4 loads in flight. Hot operands
// (wc/v/cb) deliberately NOT hoisted/staged: L1 sustains them (~39 TB/s
// aggregate) -- every reuse-hoist attempt (r6/r8/r9) lost parallelism
// and regressed.
__global__ __launch_bounds__(256, 4) void et_kernel(
    const float* __restrict__ enc,       // [B, S, H2]
    const float* __restrict__ coverage,  // [B, S]
    const float* __restrict__ W_c,       // [H2]
    const float* __restrict__ v,         // [H2]
    const float* __restrict__ combined,  // [B, H2]
    float* __restrict__ e_out)           // [B, S]
{
    const int tid  = threadIdx.x;
    const int row  = blockIdx.x * 4 + (tid >> 6);   // 4 rows per block
    const int b    = row >> 10;                     // S = 1024
    const int lane = tid & 63;

    const f4* e4   = (const f4*)enc + (size_t)row * (H2_ / 4);
    const f4* com4 = (const f4*)(combined + (size_t)b * H2_);
    const f4* wc4  = (const f4*)W_c;
    const f4* v4   = (const f4*)v;

    const float cov = coverage[row];

    float acc = 0.0f;
    #pragma unroll
    for (int i = 0; i < 4; ++i) {
        const int idx = lane + i * 64;              // float4 index within row
        const f4 e  = e4[idx];
        const f4 w  = wc4[idx];
        const f4 vv = v4[idx];
        const f4 cb = com4[idx];
        acc = fmaf(fast_tanh(fmaf(cov, w.x, e.x) + cb.x), vv.x, acc);
        acc = fmaf(fast_tanh(fmaf(cov, w.y, e.y) + cb.y), vv.y, acc);
        acc = fmaf(fast_tanh(fmaf(cov, w.z, e.z) + cb.z), vv.z, acc);
        acc = fmaf(fast_tanh(fmaf(cov, w.w, e.w) + cb.w), vv.w, acc);
    }

    #pragma unroll
    for (int off = 32; off > 0; off >>= 1)
        acc += __shfl_xor(acc, off, 64);

    if (lane == 0)
        e_out[row] = acc;
}

// Kernel 3: masked softmax over S per batch + next_coverage.
// Single-pass (no max subtraction): |e| <= ||v||_1 ~ 26 since |tanh|<=1,
// so exp(e) is finite-safe in fp32; masked lanes contribute exactly 0.
// Vectorized f4/int4 loads and f4 stores.
// grid = B, block = 256 (4 elems per thread)
__global__ __launch_bounds__(256) void softmax_kernel(
    const float* __restrict__ e_in,      // [B, S]
    const int*   __restrict__ mask,      // [B, S]
    const float* __restrict__ coverage,  // [B, S]
    float* __restrict__ a_out,           // [B, S]
    float* __restrict__ cov_out)         // [B, S]
{
    const int b   = blockIdx.x;
    const int tid = threadIdx.x;

    const f4  ev = ((const f4*)(e_in + b * S_))[tid];
    const int4 mk = ((const int4*)(mask + b * S_))[tid];
    const f4  cv = ((const f4*)(coverage + b * S_))[tid];

    f4 p;
    p.x = (mk.x == 0) ? 0.0f : __expf(ev.x);
    p.y = (mk.y == 0) ? 0.0f : __expf(ev.y);
    p.z = (mk.z == 0) ? 0.0f : __expf(ev.z);
    p.w = (mk.w == 0) ? 0.0f : __expf(ev.w);

    float lsum = (p.x + p.y) + (p.z + p.w);
    #pragma unroll
    for (int off = 1; off < 64; off <<= 1)
        lsum += __shfl_xor(lsum, off, 64);

    __shared__ float red[4];
    if ((tid & 63) == 0) red[tid >> 6] = lsum;
    __syncthreads();
    const float tot = red[0] + red[1] + red[2] + red[3];
    const float inv = 1.0f / tot;

    f4 a, nc;
    a.x = p.x * inv;  a.y = p.y * inv;  a.z = p.z * inv;  a.w = p.w * inv;
    nc.x = cv.x + a.x; nc.y = cv.y + a.y; nc.z = cv.z + a.z; nc.w = cv.w + a.w;

    ((f4*)(a_out   + b * S_))[tid] = a;
    ((f4*)(cov_out + b * S_))[tid] = nc;
}

extern "C" void kernel_launch(void* const* d_in, const int* in_sizes, int n_in,
                              void* d_out, int out_size, void* d_ws, size_t ws_size,
                              hipStream_t stream) {
    const float* enc      = (const float*)d_in[0];
    const int*   mask     = (const int*)  d_in[1];
    const float* s        = (const float*)d_in[2];
    const float* coverage = (const float*)d_in[3];
    const float* hz       = (const float*)d_in[4];
    const float* W_s      = (const float*)d_in[5];
    const float* W_c      = (const float*)d_in[6];
    const float* b_c      = (const float*)d_in[7];
    const float* W_z      = (const float*)d_in[8];
    const float* v        = (const float*)d_in[9];

    float* out_a   = (float*)d_out;            // [B, S]
    float* out_cov = out_a + B_ * S_;          // [B, S]

    float* combined = (float*)d_ws;            // [B, H2]
    float* e_ws     = combined + B_ * H2_;     // [B, S]

    combined_kernel<<<dim3(H2_ / 32, B_), 256, 0, stream>>>(s, hz, W_s, W_z, b_c, combined);
    et_kernel<<<(B_ * S_) / 4, 256, 0, stream>>>(enc, coverage, W_c, v, combined, e_ws);
    softmax_kernel<<<B_, 256, 0, stream>>>(e_ws, mask, coverage, out_a, out_cov);
}